// Round 6
// baseline (694.116 us; speedup 1.0000x reference)
//
#include <hip/hip_runtime.h>
#include <stdint.h>

#define BATCH 32
#define NV 32768
#define NF 65536
#define PCOUNT (NV*3)

// Output layout (floats, concatenated in reference return order):
// input_ids      (32, 589826)      @ 0
// attention_mask (32, 589826)      @ 18874432
// codes          (32, 65536, 3, 3) @ 37748864
// dq             (32, 65536, 3, 3) @ 56623232
// sorted_faces   (32, 65536, 3)    @ 75497600
//
// Workspace: S/FKb @0 (16MB) | S2/Q/FKa @16MB (16MB) | inv @32MB (4MB) | center | lbits
// Live ranges (stream-ordered, disjoint):
//   klocalv->S, kmergev S->S2, S2->S, kmergevQ reads S writes inv+Q.  S dead.
//   klocalfB reads Q(ws+16M), writes FKb(ws+0) + big outputs.        Q dead.
//   kmergef FKb->FKa (overlaps dead Q), FKa->FKb, kmergefOut FKb->out.

__device__ __forceinline__ unsigned fenc(float f){
  unsigned u = __float_as_uint(f);
  return (u & 0x80000000u) ? ~u : (u | 0x80000000u);
}
__device__ __forceinline__ float fdec(unsigned e){
  unsigned u = (e & 0x80000000u) ? (e & 0x7FFFFFFFu) : ~e;
  return __uint_as_float(u);
}

__global__ void kminmax(const float* __restrict__ vert, float* __restrict__ center,
                        unsigned* __restrict__ longestBits){
  int p = blockIdx.x*256 + threadIdx.x;   // 0..98303
  float mn = 3.4e38f, mx = -3.4e38f;
  #pragma unroll
  for (int b = 0; b < BATCH; ++b) {
    float v = vert[(size_t)b*PCOUNT + p];
    mn = fminf(mn, v); mx = fmaxf(mx, v);
  }
  center[p] = __fadd_rn(mn, mx) * 0.5f;
  float r = __fsub_rn(mx, mn);
  for (int off = 32; off > 0; off >>= 1) r = fmaxf(r, __shfl_down(r, off, 64));
  if ((threadIdx.x & 63) == 0) atomicMax(longestBits, __float_as_uint(r));
}

__device__ __forceinline__ bool less4(uint4 a, uint4 b){
  if (a.x != b.x) return a.x < b.x;
  if (a.y != b.y) return a.y < b.y;
  if (a.z != b.z) return a.z < b.z;
  return a.w < b.w;                        // idx: unique -> total order
}
// Face record: lo=(r0<<15)|f, hi=(r2<<15)|r1 -> compare hi then lo == (r2,r1,r0,f).
__device__ __forceinline__ bool less2(uint2 a, uint2 b){
  if (a.y != b.y) return a.y < b.y;
  return a.x < b.x;                        // f: unique -> total order
}

// ---------------- Register-blocksort local sorts -----------------------------
#define VT 4096   // vertex tile (512 thr x 8/thread)
#define FT 8192   // face tile  (512 thr x 16/thread)
#define SWV(i) ((i) ^ (((i) >> 3) & 7))     // uint4: spread bank-quads
#define SWF(i) ((i) ^ (((i) >> 4) & 15))    // uint2: spread bank-pairs

// Fused kvkeys + blocksort: build {fenc(z),fenc(y),fenc(x),idx}, sort tile, write S.
__global__ __launch_bounds__(512) void klocalv(const float* __restrict__ vert,
                                               const float* __restrict__ center,
                                               const unsigned* __restrict__ longestBits,
                                               uint4* __restrict__ S){
  __shared__ uint4 sh[VT];                  // 64 KB
  int blockBase = blockIdx.x * VT;          // tiles never cross batch boundary
  float L = __uint_as_float(*longestBits);
  float rl = __fdiv_rn(1.0f, L);
  for (int i = threadIdx.x; i < VT; i += 512){
    int id = blockBase + i;
    int vi = id & (NV-1);
    size_t vb = (size_t)(id >> 15)*PCOUNT + (size_t)vi*3;
    float nx = __fsub_rn(vert[vb+0], center[vi*3+0]);
    float ny = __fsub_rn(vert[vb+1], center[vi*3+1]);
    float nz = __fsub_rn(vert[vb+2], center[vi*3+2]);
    float x = __fmul_rn(nx, rl);
    float y = __fmul_rn(ny, rl);
    float z = __fmul_rn(nz, rl);
    uint4 s; s.x = fenc(z); s.y = fenc(y); s.z = fenc(x); s.w = (unsigned)vi;
    sh[SWV(i)] = s;
  }
  __syncthreads();
  int t = threadIdx.x;
  int k0 = t * 8;
  uint4 v[8];
  #pragma unroll
  for (int e = 0; e < 8; ++e) v[e] = sh[SWV(k0 + e)];
  // in-register bitonic sort of 8 (all indices compile-time)
  #pragma unroll
  for (int k = 2; k <= 8; k <<= 1){
    #pragma unroll
    for (int j = k >> 1; j > 0; j >>= 1){
      #pragma unroll
      for (int i = 0; i < 8; ++i){
        int l = i ^ j;
        if (l > i){
          bool up = ((i & k) == 0);
          bool sw = up ? less4(v[l], v[i]) : less4(v[i], v[l]);
          if (sw){ uint4 tmp = v[i]; v[i] = v[l]; v[l] = tmp; }
        }
      }
    }
  }
  #pragma unroll
  for (int e = 0; e < 8; ++e) sh[SWV(k0 + e)] = v[e];
  __syncthreads();
  // LDS merge-path rounds: run width w -> 2w
  for (int w = 8; w < VT; w <<= 1){
    int base = k0 & ~(2*w - 1);
    int ko = k0 - base;
    int lo = ko - w; if (lo < 0) lo = 0;
    int hi = ko < w ? ko : w;
    while (lo < hi){
      int mid = (lo + hi) >> 1;
      if (less4(sh[SWV(base + mid)], sh[SWV(base + w + ko-1-mid)])) lo = mid + 1; else hi = mid;
    }
    int i = lo, j = ko - lo;
    uint4 m[8];
    #pragma unroll
    for (int e = 0; e < 8; ++e){
      bool takeA = (j >= w) || (i < w && less4(sh[SWV(base + i)], sh[SWV(base + w + j)]));
      m[e] = takeA ? sh[SWV(base + i)] : sh[SWV(base + w + j)];
      if (takeA) ++i; else ++j;
    }
    __syncthreads();
    #pragma unroll
    for (int e = 0; e < 8; ++e) sh[SWV(k0 + e)] = m[e];
    __syncthreads();
  }
  uint4* basep = S + (size_t)blockBase;
  for (int i = threadIdx.x; i < VT; i += 512) basep[i] = sh[SWV(i)];
}

// ---------------- LDS-staged merge-path merge rounds --------------------------
__global__ __launch_bounds__(256) void kmergev(const uint4* __restrict__ src,
                                               uint4* __restrict__ dst, int L){
  __shared__ uint4 sh[2048];
  __shared__ int sAB[2];
  int gid = blockIdx.x;
  int b = gid >> 4, c = gid & 15;
  const uint4* base = src + ((size_t)b << 15);
  uint4* obase = dst + ((size_t)b << 15);
  int co = c * 2048;
  int pair = co / (2*L);
  int ko = co - pair*2*L;
  const uint4* A = base + (size_t)pair*2*L;
  const uint4* B = A + L;
  uint4* O = obase + (size_t)pair*2*L + ko;
  if (threadIdx.x < 2){
    int k = ko + (int)threadIdx.x * 2048;
    int lo = k - L; if (lo < 0) lo = 0;
    int hi = k < L ? k : L;
    while (lo < hi){
      int mid = (lo + hi) >> 1;
      if (less4(A[mid], B[k-1-mid])) lo = mid + 1; else hi = mid;
    }
    sAB[threadIdx.x] = lo;
  }
  __syncthreads();
  int aStart = sAB[0];
  int na = sAB[1] - aStart;
  int nb = 2048 - na;
  int bStart = ko - aStart;
  for (int i = threadIdx.x; i < 2048; i += 256)
    sh[i] = (i < na) ? A[aStart + i] : B[bStart + (i - na)];
  __syncthreads();
  int k0 = threadIdx.x * 8;
  int lo = k0 - nb; if (lo < 0) lo = 0;
  int hi = k0 < na ? k0 : na;
  while (lo < hi){
    int mid = (lo + hi) >> 1;
    if (less4(sh[mid], sh[na + k0-1-mid])) lo = mid + 1; else hi = mid;
  }
  int i = lo, j = k0 - lo;
  #pragma unroll
  for (int e = 0; e < 8; ++e){
    bool takeA = (j >= nb) || (i < na && less4(sh[i], sh[na + j]));
    uint4 v = takeA ? sh[i] : sh[na + j];
    if (takeA) ++i; else ++j;
    O[k0 + e] = v;
  }
}

// Final vertex merge (L=16384) fused with inverse-permutation + packed quant
// table: the merged record never round-trips through global sorted S.
__global__ __launch_bounds__(256) void kmergevQ(const uint4* __restrict__ src,
                                                int* __restrict__ inv,
                                                unsigned* __restrict__ Q){
  #pragma clang fp contract(off)
  __shared__ uint4 sh[2048];
  __shared__ int sAB[2];
  const int L = 16384;
  int gid = blockIdx.x;
  int b = gid >> 4, c = gid & 15;
  const uint4* A = src + ((size_t)b << 15);
  const uint4* B = A + L;
  int ko = c * 2048;                          // pair==0 (2L == NV)
  if (threadIdx.x < 2){
    int k = ko + (int)threadIdx.x * 2048;
    int lo = k - L; if (lo < 0) lo = 0;
    int hi = k < L ? k : L;
    while (lo < hi){
      int mid = (lo + hi) >> 1;
      if (less4(A[mid], B[k-1-mid])) lo = mid + 1; else hi = mid;
    }
    sAB[threadIdx.x] = lo;
  }
  __syncthreads();
  int aStart = sAB[0];
  int na = sAB[1] - aStart;
  int nb = 2048 - na;
  int bStart = ko - aStart;
  for (int i = threadIdx.x; i < 2048; i += 256)
    sh[i] = (i < na) ? A[aStart + i] : B[bStart + (i - na)];
  __syncthreads();
  int k0 = threadIdx.x * 8;
  int lo = k0 - nb; if (lo < 0) lo = 0;
  int hi = k0 < na ? k0 : na;
  while (lo < hi){
    int mid = (lo + hi) >> 1;
    if (less4(sh[mid], sh[na + k0-1-mid])) lo = mid + 1; else hi = mid;
  }
  int i = lo, j = k0 - lo;
  #pragma unroll
  for (int e = 0; e < 8; ++e){
    bool takeA = (j >= nb) || (i < na && less4(sh[i], sh[na + j]));
    uint4 s = takeA ? sh[i] : sh[na + j];
    if (takeA) ++i; else ++j;
    int pos = ko + k0 + e;                    // final sorted index within batch
    inv[(b<<15) + (int)s.w] = pos;
    float cco[3]; cco[0] = fdec(s.z); cco[1] = fdec(s.y); cco[2] = fdec(s.x); // (x,y,z)
    unsigned qw = 0;
    #pragma unroll
    for (int cc = 0; cc < 3; ++cc){
      float tt = ((cco[cc] + 1.0f) * 0.5f) * 128.0f - 0.5f;
      float rq = rintf(tt);
      int qi = (int)rq;
      qi = qi < 0 ? 0 : (qi > 127 ? 127 : qi);
      qw |= ((unsigned)qi) << (8*cc);
    }
    Q[(b<<15) + pos] = qw;
  }
}

// Fused face keygen + OUTPUT EMISSION + blocksort.
// Chunk loop (16 x 512 faces): read faces once, build FK records into registers
// (statically indexed via full unroll), gather Q, stage 512x9 floats in LDS
// (aliases the FK buffer - records aren't in LDS until after the loop), emit
// codes/dq/ids/attn with lane-dense stores. Then register-bitonic + LDS
// merge-path sort runs while the ~1.2MB/block of stores drain asynchronously.
__global__ __launch_bounds__(512) void klocalfB(const int* __restrict__ faces,
                                                const int* __restrict__ inv,
                                                const unsigned* __restrict__ Qt,
                                                uint2* __restrict__ F,
                                                float* __restrict__ out){
  __shared__ __align__(16) uint2 sh[FT];      // 64 KB; first 20KB doubles as scratch
  float* shq = (float*)sh;                    // [4608] staging (18 KB)
  float* shm = ((float*)sh) + 4608;           // [512] masks (2 KB)
  int blockBase = blockIdx.x * FT;            // tiles never cross batch boundary
  int b = blockBase >> 16;
  const int* invb = inv + (b << 15);
  const unsigned* Qb = Qt + (b << 15);
  int t = threadIdx.x;
  uint2 v[16];
  #pragma unroll 16
  for (int c = 0; c < 16; ++c){
    int i = c*512 + t;
    int id = blockBase + i;
    int f = id & (NF-1);
    size_t fb = (size_t)id*3;
    int f0 = faces[fb+0], f1 = faces[fb+1], f2 = faces[fb+2];
    bool mask = (f0 != -1) & (f1 != -1) & (f2 != -1);
    unsigned r0 = (unsigned)invb[f0 & (NV-1)];
    unsigned r1 = (unsigned)invb[f1 & (NV-1)];
    unsigned r2 = (unsigned)invb[f2 & (NV-1)];
    v[c].x = (r0 << 15) | (unsigned)f;
    v[c].y = (r2 << 15) | r1;
    unsigned qw0 = Qb[mask ? f0 : 0];
    unsigned qw1 = Qb[mask ? f1 : 0];
    unsigned qw2 = Qb[mask ? f2 : 0];
    shm[t] = mask ? 1.0f : 0.0f;
    shq[t*9+0] = (float)( qw0        & 255u);
    shq[t*9+1] = (float)((qw0 >> 8 ) & 255u);
    shq[t*9+2] = (float)((qw0 >> 16) & 255u);
    shq[t*9+3] = (float)( qw1        & 255u);
    shq[t*9+4] = (float)((qw1 >> 8 ) & 255u);
    shq[t*9+5] = (float)((qw1 >> 16) & 255u);
    shq[t*9+6] = (float)( qw2        & 255u);
    shq[t*9+7] = (float)((qw2 >> 8 ) & 255u);
    shq[t*9+8] = (float)((qw2 >> 16) & 255u);
    __syncthreads();
    // codes/dq: 16B-aligned chunk bases -> float4 stores (1152 per chunk)
    float4* cp = (float4*)(out + 37748864 + ((size_t)blockBase + c*512)*9);
    float4* dp = (float4*)(out + 56623232 + ((size_t)blockBase + c*512)*9);
    for (int r = t; r < 1152; r += 512){
      int e0 = r*4;
      float4 q = *(const float4*)&shq[e0];
      float m0 = shm[(unsigned)(e0  )/9u];
      float m1 = shm[(unsigned)(e0+1)/9u];
      float m2 = shm[(unsigned)(e0+2)/9u];
      float m3 = shm[(unsigned)(e0+3)/9u];
      float4 cv;
      cv.x = m0 != 0.0f ? q.x : -1.0f;
      cv.y = m1 != 0.0f ? q.y : -1.0f;
      cv.z = m2 != 0.0f ? q.z : -1.0f;
      cv.w = m3 != 0.0f ? q.w : -1.0f;
      cp[r] = cv;
      dp[r] = q;
    }
    // ids/attn: +1 float offset (misaligned) -> dense scalar dword stores
    size_t fi = (size_t)(blockBase & (NF-1)) + (size_t)c*512;  // within batch
    size_t idsBase  = (size_t)b*589826 + 1 + fi*9;
    size_t attnBase = 18874432 + idsBase;
    #pragma unroll
    for (int r = 0; r < 9; ++r){
      int idx = r*512 + t;
      float q = shq[idx];
      float m = shm[(unsigned)idx/9u];
      out[idsBase + idx]  = m != 0.0f ? q : -1.0f;
      out[attnBase + idx] = m;
    }
    __syncthreads();                          // shq/shm reuse (and final: FK reuse)
  }
  if ((blockBase & (NF-1)) == 0 && t == 0){
    out[(size_t)b*589826]                     = -1.0f;
    out[(size_t)b*589826 + 589825]            = -1.0f;
    out[18874432 + (size_t)b*589826]          = -1.0f;
    out[18874432 + (size_t)b*589826 + 589825] = -1.0f;
  }
  // in-register bitonic sort of 16 (any 16 elements -> sorted run; total order
  // makes the final sorted tile independent of initial placement)
  #pragma unroll
  for (int k = 2; k <= 16; k <<= 1){
    #pragma unroll
    for (int j = k >> 1; j > 0; j >>= 1){
      #pragma unroll
      for (int i = 0; i < 16; ++i){
        int l = i ^ j;
        if (l > i){
          bool up = ((i & k) == 0);
          bool sw = up ? less2(v[l], v[i]) : less2(v[i], v[l]);
          if (sw){ uint2 tmp = v[i]; v[i] = v[l]; v[l] = tmp; }
        }
      }
    }
  }
  int k0 = t * 16;
  #pragma unroll
  for (int e = 0; e < 16; ++e) sh[SWF(k0 + e)] = v[e];
  __syncthreads();
  for (int w = 16; w < FT; w <<= 1){
    int base = k0 & ~(2*w - 1);
    int ko = k0 - base;
    int lo = ko - w; if (lo < 0) lo = 0;
    int hi = ko < w ? ko : w;
    while (lo < hi){
      int mid = (lo + hi) >> 1;
      if (less2(sh[SWF(base + mid)], sh[SWF(base + w + ko-1-mid)])) lo = mid + 1; else hi = mid;
    }
    int i = lo, j = ko - lo;
    uint2 m[16];
    #pragma unroll
    for (int e = 0; e < 16; ++e){
      bool takeA = (j >= w) || (i < w && less2(sh[SWF(base + i)], sh[SWF(base + w + j)]));
      m[e] = takeA ? sh[SWF(base + i)] : sh[SWF(base + w + j)];
      if (takeA) ++i; else ++j;
    }
    __syncthreads();
    #pragma unroll
    for (int e = 0; e < 16; ++e) sh[SWF(k0 + e)] = m[e];
    __syncthreads();
  }
  uint2* basep = F + (size_t)blockBase;
  for (int i = threadIdx.x; i < FT; i += 512) basep[i] = sh[SWF(i)];
}

__global__ __launch_bounds__(256) void kmergef(const uint2* __restrict__ src,
                                               uint2* __restrict__ dst, int L){
  __shared__ uint2 sh[2048];
  __shared__ int sAB[2];
  int gid = blockIdx.x;
  int b = gid >> 5, c = gid & 31;
  const uint2* base = src + ((size_t)b << 16);
  uint2* obase = dst + ((size_t)b << 16);
  int co = c * 2048;
  int pair = co / (2*L);
  int ko = co - pair*2*L;
  const uint2* A = base + (size_t)pair*2*L;
  const uint2* B = A + L;
  uint2* O = obase + (size_t)pair*2*L + ko;
  if (threadIdx.x < 2){
    int k = ko + (int)threadIdx.x * 2048;
    int lo = k - L; if (lo < 0) lo = 0;
    int hi = k < L ? k : L;
    while (lo < hi){
      int mid = (lo + hi) >> 1;
      if (less2(A[mid], B[k-1-mid])) lo = mid + 1; else hi = mid;
    }
    sAB[threadIdx.x] = lo;
  }
  __syncthreads();
  int aStart = sAB[0];
  int na = sAB[1] - aStart;
  int nb = 2048 - na;
  int bStart = ko - aStart;
  for (int i = threadIdx.x; i < 2048; i += 256)
    sh[i] = (i < na) ? A[aStart + i] : B[bStart + (i - na)];
  __syncthreads();
  int k0 = threadIdx.x * 8;
  int lo = k0 - nb; if (lo < 0) lo = 0;
  int hi = k0 < na ? k0 : na;
  while (lo < hi){
    int mid = (lo + hi) >> 1;
    if (less2(sh[mid], sh[na + k0-1-mid])) lo = mid + 1; else hi = mid;
  }
  int i = lo, j = k0 - lo;
  #pragma unroll
  for (int e = 0; e < 8; ++e){
    bool takeA = (j >= nb) || (i < na && less2(sh[i], sh[na + j]));
    uint2 v = takeA ? sh[i] : sh[na + j];
    if (takeA) ++i; else ++j;
    O[k0 + e] = v;
  }
}

// Final face merge (L=32768): merge in LDS, decode ranks, write sorted_faces
// floats directly (3 dense streams).
__global__ __launch_bounds__(256) void kmergefOut(const uint2* __restrict__ src,
                                                  float* __restrict__ out){
  __shared__ __align__(16) float shf[6144];   // 24 KB; aliased as uint2[2048] below
  __shared__ int sAB[2];
  uint2* sh = (uint2*)shf;
  const int L = 32768;
  int gid = blockIdx.x;                       // 1024 = 32 batches x 32 chunks
  int b = gid >> 5, c = gid & 31;
  const uint2* A = src + ((size_t)b << 16);
  const uint2* B = A + L;
  int ko = c * 2048;
  if (threadIdx.x < 2){
    int k = ko + (int)threadIdx.x * 2048;
    int lo = k - L; if (lo < 0) lo = 0;
    int hi = k < L ? k : L;
    while (lo < hi){
      int mid = (lo + hi) >> 1;
      if (less2(A[mid], B[k-1-mid])) lo = mid + 1; else hi = mid;
    }
    sAB[threadIdx.x] = lo;
  }
  __syncthreads();
  int aStart = sAB[0];
  int na = sAB[1] - aStart;
  int nb = 2048 - na;
  int bStart = ko - aStart;
  for (int i = threadIdx.x; i < 2048; i += 256)
    sh[i] = (i < na) ? A[aStart + i] : B[bStart + (i - na)];
  __syncthreads();
  int k0 = threadIdx.x * 8;
  int lo = k0 - nb; if (lo < 0) lo = 0;
  int hi = k0 < na ? k0 : na;
  while (lo < hi){
    int mid = (lo + hi) >> 1;
    if (less2(sh[mid], sh[na + k0-1-mid])) lo = mid + 1; else hi = mid;
  }
  int i = lo, j = k0 - lo;
  uint2 v[8];
  #pragma unroll
  for (int e = 0; e < 8; ++e){
    bool takeA = (j >= nb) || (i < na && less2(sh[i], sh[na + j]));
    v[e] = takeA ? sh[i] : sh[na + j];
    if (takeA) ++i; else ++j;
  }
  __syncthreads();                            // all LDS src reads done
  #pragma unroll
  for (int e = 0; e < 8; ++e){
    int o = (k0 + e) * 3;
    shf[o+0] = (float)(v[e].x >> 15);         // r0
    shf[o+1] = (float)(v[e].y & 0x7FFFu);     // r1
    shf[o+2] = (float)(v[e].y >> 15);         // r2
  }
  __syncthreads();
  size_t basef = 75497600 + ((size_t)b*65536 + (size_t)ko)*3;
  for (int q = threadIdx.x; q < 6144; q += 256) out[basef + q] = shf[q];
}
// -----------------------------------------------------------------------------

extern "C" void kernel_launch(void* const* d_in, const int* in_sizes, int n_in,
                              void* d_out, int out_size, void* d_ws, size_t ws_size,
                              hipStream_t stream){
  const float* vert  = (const float*)d_in[0];
  const int*   faces = (const int*)d_in[1];
  float* out = (float*)d_out;

  uint4*    S           = (uint4*)d_ws;                         // 16 MiB
  uint4*    S2          = (uint4*)((char*)d_ws + 16777216);     // 16 MiB
  uint2*    FKa         = (uint2*)((char*)d_ws + 16777216);     // reuses S2
  unsigned* Q           = (unsigned*)((char*)d_ws + 16777216);  // aliases FKa (4 MiB)
  uint2*    FKb         = (uint2*)d_ws;                         // reuses S
  int*      inv         = (int*)((char*)d_ws + 33554432);       // 4 MiB
  float*    center      = (float*)((char*)d_ws + 37748736);     // 384 KiB
  unsigned* longestBits = (unsigned*)((char*)d_ws + 38141952);  // 4 B

  hipMemsetAsync(longestBits, 0, 4, stream);
  kminmax<<<PCOUNT/256, 256, 0, stream>>>(vert, center, longestBits);

  // vertex sort: fused keygen + blocksort 4096-tiles, 2 merge rounds,
  // final round fused with inv+Q emission (sorted S never re-materialized)
  klocalv<<<BATCH*(NV/VT), 512, 0, stream>>>(vert, center, longestBits, S);
  kmergev<<<BATCH*16, 256, 0, stream>>>(S,  S2, 4096);
  kmergev<<<BATCH*16, 256, 0, stream>>>(S2, S,  8192);
  kmergevQ<<<BATCH*16, 256, 0, stream>>>(S, inv, Q);            // S dead after

  // fused face keygen + output emission + blocksort (overlaps stores w/ sort)
  klocalfB<<<BATCH*(NF/FT), 512, 0, stream>>>(faces, inv, Q, FKb, out);  // Q dead

  kmergef<<<BATCH*32, 256, 0, stream>>>(FKb, FKa, 8192);
  kmergef<<<BATCH*32, 256, 0, stream>>>(FKa, FKb, 16384);
  kmergefOut<<<BATCH*32, 256, 0, stream>>>(FKb, out);
}

// Round 7
// 598.988 us; speedup vs baseline: 1.1588x; 1.1588x over previous
//
#include <hip/hip_runtime.h>
#include <stdint.h>

#define BATCH 32
#define NV 32768
#define NF 65536
#define PCOUNT (NV*3)

// Output layout (floats, concatenated in reference return order):
// input_ids      (32, 589826)      @ 0
// attention_mask (32, 589826)      @ 18874432
// codes          (32, 65536, 3, 3) @ 37748864
// dq             (32, 65536, 3, 3) @ 56623232
// sorted_faces   (32, 65536, 3)    @ 75497600
//
// Workspace: S/FKb @0 (16MB) | S2/Q/FKa @16MB (16MB) | inv @32MB (4MB) | center | lbits
// Live ranges (stream-ordered, disjoint):
//   klocalv->S, kmergev S->S2, S2->S, kmergevQ reads S writes inv+Q.  S dead.
//   klocalfB reads Q(ws+16M), writes FKb(ws+0) + big outputs.        Q dead.
//   kmergef FKb->FKa (overlaps dead Q), FKa->FKb, kmergefOut FKb->out.

__device__ __forceinline__ unsigned fenc(float f){
  unsigned u = __float_as_uint(f);
  return (u & 0x80000000u) ? ~u : (u | 0x80000000u);
}
__device__ __forceinline__ float fdec(unsigned e){
  unsigned u = (e & 0x80000000u) ? (e & 0x7FFFFFFFu) : ~e;
  return __uint_as_float(u);
}

__global__ void kminmax(const float* __restrict__ vert, float* __restrict__ center,
                        unsigned* __restrict__ longestBits){
  int p = blockIdx.x*256 + threadIdx.x;   // 0..98303
  float mn = 3.4e38f, mx = -3.4e38f;
  #pragma unroll
  for (int b = 0; b < BATCH; ++b) {
    float v = vert[(size_t)b*PCOUNT + p];
    mn = fminf(mn, v); mx = fmaxf(mx, v);
  }
  center[p] = __fadd_rn(mn, mx) * 0.5f;
  float r = __fsub_rn(mx, mn);
  for (int off = 32; off > 0; off >>= 1) r = fmaxf(r, __shfl_down(r, off, 64));
  if ((threadIdx.x & 63) == 0) atomicMax(longestBits, __float_as_uint(r));
}

__device__ __forceinline__ bool less4(uint4 a, uint4 b){
  if (a.x != b.x) return a.x < b.x;
  if (a.y != b.y) return a.y < b.y;
  if (a.z != b.z) return a.z < b.z;
  return a.w < b.w;                        // idx: unique -> total order
}
// Face record: lo=(r0<<15)|f, hi=(r2<<15)|r1 -> compare hi then lo == (r2,r1,r0,f).
__device__ __forceinline__ bool less2(uint2 a, uint2 b){
  if (a.y != b.y) return a.y < b.y;
  return a.x < b.x;                        // f: unique -> total order
}

// ---------------- Register-blocksort local sorts -----------------------------
#define VT 4096   // vertex tile (512 thr x 8/thread)
#define FT 8192   // face tile  (512 thr x 16/thread)
#define SWV(i) ((i) ^ (((i) >> 3) & 7))     // uint4: spread bank-quads
#define SWF(i) ((i) ^ (((i) >> 4) & 15))    // uint2: spread bank-pairs

// Fused kvkeys + blocksort: build {fenc(z),fenc(y),fenc(x),idx}, sort tile, write S.
__global__ __launch_bounds__(512) void klocalv(const float* __restrict__ vert,
                                               const float* __restrict__ center,
                                               const unsigned* __restrict__ longestBits,
                                               uint4* __restrict__ S){
  __shared__ uint4 sh[VT];                  // 64 KB
  int blockBase = blockIdx.x * VT;          // tiles never cross batch boundary
  float L = __uint_as_float(*longestBits);
  float rl = __fdiv_rn(1.0f, L);
  for (int i = threadIdx.x; i < VT; i += 512){
    int id = blockBase + i;
    int vi = id & (NV-1);
    size_t vb = (size_t)(id >> 15)*PCOUNT + (size_t)vi*3;
    float nx = __fsub_rn(vert[vb+0], center[vi*3+0]);
    float ny = __fsub_rn(vert[vb+1], center[vi*3+1]);
    float nz = __fsub_rn(vert[vb+2], center[vi*3+2]);
    float x = __fmul_rn(nx, rl);
    float y = __fmul_rn(ny, rl);
    float z = __fmul_rn(nz, rl);
    uint4 s; s.x = fenc(z); s.y = fenc(y); s.z = fenc(x); s.w = (unsigned)vi;
    sh[SWV(i)] = s;
  }
  __syncthreads();
  int t = threadIdx.x;
  int k0 = t * 8;
  uint4 v[8];
  #pragma unroll
  for (int e = 0; e < 8; ++e) v[e] = sh[SWV(k0 + e)];
  // in-register bitonic sort of 8 (all indices compile-time)
  #pragma unroll
  for (int k = 2; k <= 8; k <<= 1){
    #pragma unroll
    for (int j = k >> 1; j > 0; j >>= 1){
      #pragma unroll
      for (int i = 0; i < 8; ++i){
        int l = i ^ j;
        if (l > i){
          bool up = ((i & k) == 0);
          bool sw = up ? less4(v[l], v[i]) : less4(v[i], v[l]);
          if (sw){ uint4 tmp = v[i]; v[i] = v[l]; v[l] = tmp; }
        }
      }
    }
  }
  #pragma unroll
  for (int e = 0; e < 8; ++e) sh[SWV(k0 + e)] = v[e];
  __syncthreads();
  // LDS merge-path rounds: run width w -> 2w
  for (int w = 8; w < VT; w <<= 1){
    int base = k0 & ~(2*w - 1);
    int ko = k0 - base;
    int lo = ko - w; if (lo < 0) lo = 0;
    int hi = ko < w ? ko : w;
    while (lo < hi){
      int mid = (lo + hi) >> 1;
      if (less4(sh[SWV(base + mid)], sh[SWV(base + w + ko-1-mid)])) lo = mid + 1; else hi = mid;
    }
    int i = lo, j = ko - lo;
    uint4 m[8];
    #pragma unroll
    for (int e = 0; e < 8; ++e){
      bool takeA = (j >= w) || (i < w && less4(sh[SWV(base + i)], sh[SWV(base + w + j)]));
      m[e] = takeA ? sh[SWV(base + i)] : sh[SWV(base + w + j)];
      if (takeA) ++i; else ++j;
    }
    __syncthreads();
    #pragma unroll
    for (int e = 0; e < 8; ++e) sh[SWV(k0 + e)] = m[e];
    __syncthreads();
  }
  uint4* basep = S + (size_t)blockBase;
  for (int i = threadIdx.x; i < VT; i += 512) basep[i] = sh[SWV(i)];
}

// ---------------- LDS-staged merge-path merge rounds --------------------------
__global__ __launch_bounds__(256) void kmergev(const uint4* __restrict__ src,
                                               uint4* __restrict__ dst, int L){
  __shared__ uint4 sh[2048];
  __shared__ int sAB[2];
  int gid = blockIdx.x;
  int b = gid >> 4, c = gid & 15;
  const uint4* base = src + ((size_t)b << 15);
  uint4* obase = dst + ((size_t)b << 15);
  int co = c * 2048;
  int pair = co / (2*L);
  int ko = co - pair*2*L;
  const uint4* A = base + (size_t)pair*2*L;
  const uint4* B = A + L;
  uint4* O = obase + (size_t)pair*2*L + ko;
  if (threadIdx.x < 2){
    int k = ko + (int)threadIdx.x * 2048;
    int lo = k - L; if (lo < 0) lo = 0;
    int hi = k < L ? k : L;
    while (lo < hi){
      int mid = (lo + hi) >> 1;
      if (less4(A[mid], B[k-1-mid])) lo = mid + 1; else hi = mid;
    }
    sAB[threadIdx.x] = lo;
  }
  __syncthreads();
  int aStart = sAB[0];
  int na = sAB[1] - aStart;
  int nb = 2048 - na;
  int bStart = ko - aStart;
  for (int i = threadIdx.x; i < 2048; i += 256)
    sh[i] = (i < na) ? A[aStart + i] : B[bStart + (i - na)];
  __syncthreads();
  int k0 = threadIdx.x * 8;
  int lo = k0 - nb; if (lo < 0) lo = 0;
  int hi = k0 < na ? k0 : na;
  while (lo < hi){
    int mid = (lo + hi) >> 1;
    if (less4(sh[mid], sh[na + k0-1-mid])) lo = mid + 1; else hi = mid;
  }
  int i = lo, j = k0 - lo;
  #pragma unroll
  for (int e = 0; e < 8; ++e){
    bool takeA = (j >= nb) || (i < na && less4(sh[i], sh[na + j]));
    uint4 v = takeA ? sh[i] : sh[na + j];
    if (takeA) ++i; else ++j;
    O[k0 + e] = v;
  }
}

// Final vertex merge (L=16384) fused with inverse-permutation + packed quant
// table: the merged record never round-trips through global sorted S.
__global__ __launch_bounds__(256) void kmergevQ(const uint4* __restrict__ src,
                                                int* __restrict__ inv,
                                                unsigned* __restrict__ Q){
  #pragma clang fp contract(off)
  __shared__ uint4 sh[2048];
  __shared__ int sAB[2];
  const int L = 16384;
  int gid = blockIdx.x;
  int b = gid >> 4, c = gid & 15;
  const uint4* A = src + ((size_t)b << 15);
  const uint4* B = A + L;
  int ko = c * 2048;                          // pair==0 (2L == NV)
  if (threadIdx.x < 2){
    int k = ko + (int)threadIdx.x * 2048;
    int lo = k - L; if (lo < 0) lo = 0;
    int hi = k < L ? k : L;
    while (lo < hi){
      int mid = (lo + hi) >> 1;
      if (less4(A[mid], B[k-1-mid])) lo = mid + 1; else hi = mid;
    }
    sAB[threadIdx.x] = lo;
  }
  __syncthreads();
  int aStart = sAB[0];
  int na = sAB[1] - aStart;
  int nb = 2048 - na;
  int bStart = ko - aStart;
  for (int i = threadIdx.x; i < 2048; i += 256)
    sh[i] = (i < na) ? A[aStart + i] : B[bStart + (i - na)];
  __syncthreads();
  int k0 = threadIdx.x * 8;
  int lo = k0 - nb; if (lo < 0) lo = 0;
  int hi = k0 < na ? k0 : na;
  while (lo < hi){
    int mid = (lo + hi) >> 1;
    if (less4(sh[mid], sh[na + k0-1-mid])) lo = mid + 1; else hi = mid;
  }
  int i = lo, j = k0 - lo;
  #pragma unroll
  for (int e = 0; e < 8; ++e){
    bool takeA = (j >= nb) || (i < na && less4(sh[i], sh[na + j]));
    uint4 s = takeA ? sh[i] : sh[na + j];
    if (takeA) ++i; else ++j;
    int pos = ko + k0 + e;                    // final sorted index within batch
    inv[(b<<15) + (int)s.w] = pos;
    float cco[3]; cco[0] = fdec(s.z); cco[1] = fdec(s.y); cco[2] = fdec(s.x); // (x,y,z)
    unsigned qw = 0;
    #pragma unroll
    for (int cc = 0; cc < 3; ++cc){
      float tt = ((cco[cc] + 1.0f) * 0.5f) * 128.0f - 0.5f;
      float rq = rintf(tt);
      int qi = (int)rq;
      qi = qi < 0 ? 0 : (qi > 127 ? 127 : qi);
      qw |= ((unsigned)qi) << (8*cc);
    }
    Q[(b<<15) + pos] = qw;
  }
}

// Fused face keygen + OUTPUT EMISSION + blocksort, with XCD-affine swizzle.
// Swizzle l=(p%8)*32+p/8 (bijective, 256=8x32): XCD x serves batches 4x..4x+3
// only -> inv+Q working set 4x256KB=1MB, L2-resident (R6 regression root cause:
// without this, each XCD touched all 32 batches = 8MB > 4MB L2 -> 430MB fetch).
__global__ __launch_bounds__(512) void klocalfB(const int* __restrict__ faces,
                                                const int* __restrict__ inv,
                                                const unsigned* __restrict__ Qt,
                                                uint2* __restrict__ F,
                                                float* __restrict__ out){
  __shared__ __align__(16) uint2 sh[FT];      // 64 KB; first 20KB doubles as scratch
  float* shq = (float*)sh;                    // [4608] staging (18 KB)
  float* shm = ((float*)sh) + 4608;           // [512] masks (2 KB)
  int p = blockIdx.x;
  int l = ((p & 7) << 5) | (p >> 3);          // XCD-affine, bijective on 256
  int blockBase = l * FT;                     // tiles never cross batch boundary
  int b = blockBase >> 16;
  const int* invb = inv + (b << 15);
  const unsigned* Qb = Qt + (b << 15);
  int t = threadIdx.x;
  uint2 v[16];
  #pragma unroll 16
  for (int c = 0; c < 16; ++c){
    int i = c*512 + t;
    int id = blockBase + i;
    int f = id & (NF-1);
    size_t fb = (size_t)id*3;
    int f0 = faces[fb+0], f1 = faces[fb+1], f2 = faces[fb+2];
    bool mask = (f0 != -1) & (f1 != -1) & (f2 != -1);
    unsigned r0 = (unsigned)invb[f0 & (NV-1)];
    unsigned r1 = (unsigned)invb[f1 & (NV-1)];
    unsigned r2 = (unsigned)invb[f2 & (NV-1)];
    v[c].x = (r0 << 15) | (unsigned)f;
    v[c].y = (r2 << 15) | r1;
    unsigned qw0 = Qb[mask ? f0 : 0];
    unsigned qw1 = Qb[mask ? f1 : 0];
    unsigned qw2 = Qb[mask ? f2 : 0];
    shm[t] = mask ? 1.0f : 0.0f;
    shq[t*9+0] = (float)( qw0        & 255u);
    shq[t*9+1] = (float)((qw0 >> 8 ) & 255u);
    shq[t*9+2] = (float)((qw0 >> 16) & 255u);
    shq[t*9+3] = (float)( qw1        & 255u);
    shq[t*9+4] = (float)((qw1 >> 8 ) & 255u);
    shq[t*9+5] = (float)((qw1 >> 16) & 255u);
    shq[t*9+6] = (float)( qw2        & 255u);
    shq[t*9+7] = (float)((qw2 >> 8 ) & 255u);
    shq[t*9+8] = (float)((qw2 >> 16) & 255u);
    __syncthreads();
    // codes/dq: 16B-aligned chunk bases -> float4 stores (1152 per chunk)
    float4* cp = (float4*)(out + 37748864 + ((size_t)blockBase + c*512)*9);
    float4* dp = (float4*)(out + 56623232 + ((size_t)blockBase + c*512)*9);
    for (int r = t; r < 1152; r += 512){
      int e0 = r*4;
      float4 q = *(const float4*)&shq[e0];
      float m0 = shm[(unsigned)(e0  )/9u];
      float m1 = shm[(unsigned)(e0+1)/9u];
      float m2 = shm[(unsigned)(e0+2)/9u];
      float m3 = shm[(unsigned)(e0+3)/9u];
      float4 cv;
      cv.x = m0 != 0.0f ? q.x : -1.0f;
      cv.y = m1 != 0.0f ? q.y : -1.0f;
      cv.z = m2 != 0.0f ? q.z : -1.0f;
      cv.w = m3 != 0.0f ? q.w : -1.0f;
      cp[r] = cv;
      dp[r] = q;
    }
    // ids/attn: +1 float offset (misaligned) -> dense scalar dword stores
    size_t fi = (size_t)(blockBase & (NF-1)) + (size_t)c*512;  // within batch
    size_t idsBase  = (size_t)b*589826 + 1 + fi*9;
    size_t attnBase = 18874432 + idsBase;
    #pragma unroll
    for (int r = 0; r < 9; ++r){
      int idx = r*512 + t;
      float q = shq[idx];
      float m = shm[(unsigned)idx/9u];
      out[idsBase + idx]  = m != 0.0f ? q : -1.0f;
      out[attnBase + idx] = m;
    }
    __syncthreads();                          // shq/shm reuse (and final: FK reuse)
  }
  if ((blockBase & (NF-1)) == 0 && t == 0){
    out[(size_t)b*589826]                     = -1.0f;
    out[(size_t)b*589826 + 589825]            = -1.0f;
    out[18874432 + (size_t)b*589826]          = -1.0f;
    out[18874432 + (size_t)b*589826 + 589825] = -1.0f;
  }
  // in-register bitonic sort of 16 (any 16 elements -> sorted run; total order
  // makes the final sorted tile independent of initial placement)
  #pragma unroll
  for (int k = 2; k <= 16; k <<= 1){
    #pragma unroll
    for (int j = k >> 1; j > 0; j >>= 1){
      #pragma unroll
      for (int i = 0; i < 16; ++i){
        int l2 = i ^ j;
        if (l2 > i){
          bool up = ((i & k) == 0);
          bool sw = up ? less2(v[l2], v[i]) : less2(v[i], v[l2]);
          if (sw){ uint2 tmp = v[i]; v[i] = v[l2]; v[l2] = tmp; }
        }
      }
    }
  }
  int k0 = t * 16;
  #pragma unroll
  for (int e = 0; e < 16; ++e) sh[SWF(k0 + e)] = v[e];
  __syncthreads();
  for (int w = 16; w < FT; w <<= 1){
    int base = k0 & ~(2*w - 1);
    int ko = k0 - base;
    int lo = ko - w; if (lo < 0) lo = 0;
    int hi = ko < w ? ko : w;
    while (lo < hi){
      int mid = (lo + hi) >> 1;
      if (less2(sh[SWF(base + mid)], sh[SWF(base + w + ko-1-mid)])) lo = mid + 1; else hi = mid;
    }
    int i = lo, j = ko - lo;
    uint2 m[16];
    #pragma unroll
    for (int e = 0; e < 16; ++e){
      bool takeA = (j >= w) || (i < w && less2(sh[SWF(base + i)], sh[SWF(base + w + j)]));
      m[e] = takeA ? sh[SWF(base + i)] : sh[SWF(base + w + j)];
      if (takeA) ++i; else ++j;
    }
    __syncthreads();
    #pragma unroll
    for (int e = 0; e < 16; ++e) sh[SWF(k0 + e)] = m[e];
    __syncthreads();
  }
  uint2* basep = F + (size_t)blockBase;
  for (int i = threadIdx.x; i < FT; i += 512) basep[i] = sh[SWF(i)];
}

__global__ __launch_bounds__(256) void kmergef(const uint2* __restrict__ src,
                                               uint2* __restrict__ dst, int L){
  __shared__ uint2 sh[2048];
  __shared__ int sAB[2];
  int gid = blockIdx.x;
  int b = gid >> 5, c = gid & 31;
  const uint2* base = src + ((size_t)b << 16);
  uint2* obase = dst + ((size_t)b << 16);
  int co = c * 2048;
  int pair = co / (2*L);
  int ko = co - pair*2*L;
  const uint2* A = base + (size_t)pair*2*L;
  const uint2* B = A + L;
  uint2* O = obase + (size_t)pair*2*L + ko;
  if (threadIdx.x < 2){
    int k = ko + (int)threadIdx.x * 2048;
    int lo = k - L; if (lo < 0) lo = 0;
    int hi = k < L ? k : L;
    while (lo < hi){
      int mid = (lo + hi) >> 1;
      if (less2(A[mid], B[k-1-mid])) lo = mid + 1; else hi = mid;
    }
    sAB[threadIdx.x] = lo;
  }
  __syncthreads();
  int aStart = sAB[0];
  int na = sAB[1] - aStart;
  int nb = 2048 - na;
  int bStart = ko - aStart;
  for (int i = threadIdx.x; i < 2048; i += 256)
    sh[i] = (i < na) ? A[aStart + i] : B[bStart + (i - na)];
  __syncthreads();
  int k0 = threadIdx.x * 8;
  int lo = k0 - nb; if (lo < 0) lo = 0;
  int hi = k0 < na ? k0 : na;
  while (lo < hi){
    int mid = (lo + hi) >> 1;
    if (less2(sh[mid], sh[na + k0-1-mid])) lo = mid + 1; else hi = mid;
  }
  int i = lo, j = k0 - lo;
  #pragma unroll
  for (int e = 0; e < 8; ++e){
    bool takeA = (j >= nb) || (i < na && less2(sh[i], sh[na + j]));
    uint2 v = takeA ? sh[i] : sh[na + j];
    if (takeA) ++i; else ++j;
    O[k0 + e] = v;
  }
}

// Final face merge (L=32768): merge in LDS, decode ranks, write sorted_faces
// floats directly (3 dense streams).
__global__ __launch_bounds__(256) void kmergefOut(const uint2* __restrict__ src,
                                                  float* __restrict__ out){
  __shared__ __align__(16) float shf[6144];   // 24 KB; aliased as uint2[2048] below
  __shared__ int sAB[2];
  uint2* sh = (uint2*)shf;
  const int L = 32768;
  int gid = blockIdx.x;                       // 1024 = 32 batches x 32 chunks
  int b = gid >> 5, c = gid & 31;
  const uint2* A = src + ((size_t)b << 16);
  const uint2* B = A + L;
  int ko = c * 2048;
  if (threadIdx.x < 2){
    int k = ko + (int)threadIdx.x * 2048;
    int lo = k - L; if (lo < 0) lo = 0;
    int hi = k < L ? k : L;
    while (lo < hi){
      int mid = (lo + hi) >> 1;
      if (less2(A[mid], B[k-1-mid])) lo = mid + 1; else hi = mid;
    }
    sAB[threadIdx.x] = lo;
  }
  __syncthreads();
  int aStart = sAB[0];
  int na = sAB[1] - aStart;
  int nb = 2048 - na;
  int bStart = ko - aStart;
  for (int i = threadIdx.x; i < 2048; i += 256)
    sh[i] = (i < na) ? A[aStart + i] : B[bStart + (i - na)];
  __syncthreads();
  int k0 = threadIdx.x * 8;
  int lo = k0 - nb; if (lo < 0) lo = 0;
  int hi = k0 < na ? k0 : na;
  while (lo < hi){
    int mid = (lo + hi) >> 1;
    if (less2(sh[mid], sh[na + k0-1-mid])) lo = mid + 1; else hi = mid;
  }
  int i = lo, j = k0 - lo;
  uint2 v[8];
  #pragma unroll
  for (int e = 0; e < 8; ++e){
    bool takeA = (j >= nb) || (i < na && less2(sh[i], sh[na + j]));
    v[e] = takeA ? sh[i] : sh[na + j];
    if (takeA) ++i; else ++j;
  }
  __syncthreads();                            // all LDS src reads done
  #pragma unroll
  for (int e = 0; e < 8; ++e){
    int o = (k0 + e) * 3;
    shf[o+0] = (float)(v[e].x >> 15);         // r0
    shf[o+1] = (float)(v[e].y & 0x7FFFu);     // r1
    shf[o+2] = (float)(v[e].y >> 15);         // r2
  }
  __syncthreads();
  size_t basef = 75497600 + ((size_t)b*65536 + (size_t)ko)*3;
  for (int q = threadIdx.x; q < 6144; q += 256) out[basef + q] = shf[q];
}
// -----------------------------------------------------------------------------

extern "C" void kernel_launch(void* const* d_in, const int* in_sizes, int n_in,
                              void* d_out, int out_size, void* d_ws, size_t ws_size,
                              hipStream_t stream){
  const float* vert  = (const float*)d_in[0];
  const int*   faces = (const int*)d_in[1];
  float* out = (float*)d_out;

  uint4*    S           = (uint4*)d_ws;                         // 16 MiB
  uint4*    S2          = (uint4*)((char*)d_ws + 16777216);     // 16 MiB
  uint2*    FKa         = (uint2*)((char*)d_ws + 16777216);     // reuses S2
  unsigned* Q           = (unsigned*)((char*)d_ws + 16777216);  // aliases FKa (4 MiB)
  uint2*    FKb         = (uint2*)d_ws;                         // reuses S
  int*      inv         = (int*)((char*)d_ws + 33554432);       // 4 MiB
  float*    center      = (float*)((char*)d_ws + 37748736);     // 384 KiB
  unsigned* longestBits = (unsigned*)((char*)d_ws + 38141952);  // 4 B

  hipMemsetAsync(longestBits, 0, 4, stream);
  kminmax<<<PCOUNT/256, 256, 0, stream>>>(vert, center, longestBits);

  // vertex sort: fused keygen + blocksort 4096-tiles, 2 merge rounds,
  // final round fused with inv+Q emission (sorted S never re-materialized)
  klocalv<<<BATCH*(NV/VT), 512, 0, stream>>>(vert, center, longestBits, S);
  kmergev<<<BATCH*16, 256, 0, stream>>>(S,  S2, 4096);
  kmergev<<<BATCH*16, 256, 0, stream>>>(S2, S,  8192);
  kmergevQ<<<BATCH*16, 256, 0, stream>>>(S, inv, Q);            // S dead after

  // fused face keygen + output emission + blocksort (XCD-swizzled gathers)
  klocalfB<<<BATCH*(NF/FT), 512, 0, stream>>>(faces, inv, Q, FKb, out);  // Q dead

  kmergef<<<BATCH*32, 256, 0, stream>>>(FKb, FKa, 8192);
  kmergef<<<BATCH*32, 256, 0, stream>>>(FKa, FKb, 16384);
  kmergefOut<<<BATCH*32, 256, 0, stream>>>(FKb, out);
}

// Round 8
// 595.034 us; speedup vs baseline: 1.1665x; 1.0066x over previous
//
#include <hip/hip_runtime.h>
#include <stdint.h>

#define BATCH 32
#define NV 32768
#define NF 65536
#define PCOUNT (NV*3)

// Output layout (floats, concatenated in reference return order):
// input_ids      (32, 589826)      @ 0
// attention_mask (32, 589826)      @ 18874432
// codes          (32, 65536, 3, 3) @ 37748864
// dq             (32, 65536, 3, 3) @ 56623232
// sorted_faces   (32, 65536, 3)    @ 75497600
//
// Workspace: S/FKb @0 (16MB) | S2/Q/FKa @16MB (16MB) | inv @32MB (4MB) | center | lbits
// Live ranges (stream-ordered, disjoint):
//   klocalv->S, kmergev S->S2, S2->S, kmergevQ reads S writes inv+Q.  S dead.
//   klocalfB reads Q(ws+16M), writes FKb(ws+0) + big outputs.        Q dead.
//   kmergef FKb->FKa (overlaps dead Q), FKa->FKb, kmergefOut FKb->out.

__device__ __forceinline__ unsigned fenc(float f){
  unsigned u = __float_as_uint(f);
  return (u & 0x80000000u) ? ~u : (u | 0x80000000u);
}
__device__ __forceinline__ float fdec(unsigned e){
  unsigned u = (e & 0x80000000u) ? (e & 0x7FFFFFFFu) : ~e;
  return __uint_as_float(u);
}

__global__ void kminmax(const float* __restrict__ vert, float* __restrict__ center,
                        unsigned* __restrict__ longestBits){
  int p = blockIdx.x*256 + threadIdx.x;   // 0..98303
  float mn = 3.4e38f, mx = -3.4e38f;
  #pragma unroll
  for (int b = 0; b < BATCH; ++b) {
    float v = vert[(size_t)b*PCOUNT + p];
    mn = fminf(mn, v); mx = fmaxf(mx, v);
  }
  center[p] = __fadd_rn(mn, mx) * 0.5f;
  float r = __fsub_rn(mx, mn);
  for (int off = 32; off > 0; off >>= 1) r = fmaxf(r, __shfl_down(r, off, 64));
  if ((threadIdx.x & 63) == 0) atomicMax(longestBits, __float_as_uint(r));
}

__device__ __forceinline__ bool less4(uint4 a, uint4 b){
  if (a.x != b.x) return a.x < b.x;
  if (a.y != b.y) return a.y < b.y;
  if (a.z != b.z) return a.z < b.z;
  return a.w < b.w;                        // idx: unique -> total order
}
// Face record: lo=(r0<<15)|f, hi=(r2<<15)|r1 -> compare hi then lo == (r2,r1,r0,f).
__device__ __forceinline__ bool less2(uint2 a, uint2 b){
  if (a.y != b.y) return a.y < b.y;
  return a.x < b.x;                        // f: unique -> total order
}

// ---------------- Register-blocksort local sorts -----------------------------
// 1024-thread blocks: 16 waves/CU (vs 8) on the 1-block/CU grids — the LDS
// merge-path rounds are dependent-latency chains; occupancy is the lever.
#define VT 4096   // vertex tile (1024 thr x 4/thread)
#define FT 8192   // face tile  (1024 thr x 8/thread)
#define SWV(i) ((i) ^ (((i) >> 3) & 7))     // uint4: spread bank-quads
#define SWF(i) ((i) ^ (((i) >> 4) & 15))    // uint2: spread bank-pairs

// Fused kvkeys + blocksort: build {fenc(z),fenc(y),fenc(x),idx}, sort tile, write S.
__global__ __launch_bounds__(1024) void klocalv(const float* __restrict__ vert,
                                                const float* __restrict__ center,
                                                const unsigned* __restrict__ longestBits,
                                                uint4* __restrict__ S){
  __shared__ uint4 sh[VT];                  // 64 KB
  int blockBase = blockIdx.x * VT;          // tiles never cross batch boundary
  float L = __uint_as_float(*longestBits);
  float rl = __fdiv_rn(1.0f, L);
  for (int i = threadIdx.x; i < VT; i += 1024){
    int id = blockBase + i;
    int vi = id & (NV-1);
    size_t vb = (size_t)(id >> 15)*PCOUNT + (size_t)vi*3;
    float nx = __fsub_rn(vert[vb+0], center[vi*3+0]);
    float ny = __fsub_rn(vert[vb+1], center[vi*3+1]);
    float nz = __fsub_rn(vert[vb+2], center[vi*3+2]);
    float x = __fmul_rn(nx, rl);
    float y = __fmul_rn(ny, rl);
    float z = __fmul_rn(nz, rl);
    uint4 s; s.x = fenc(z); s.y = fenc(y); s.z = fenc(x); s.w = (unsigned)vi;
    sh[SWV(i)] = s;
  }
  __syncthreads();
  int t = threadIdx.x;
  int k0 = t * 4;
  uint4 v[4];
  #pragma unroll
  for (int e = 0; e < 4; ++e) v[e] = sh[SWV(k0 + e)];
  // in-register bitonic sort of 4 (all indices compile-time)
  #pragma unroll
  for (int k = 2; k <= 4; k <<= 1){
    #pragma unroll
    for (int j = k >> 1; j > 0; j >>= 1){
      #pragma unroll
      for (int i = 0; i < 4; ++i){
        int l = i ^ j;
        if (l > i){
          bool up = ((i & k) == 0);
          bool sw = up ? less4(v[l], v[i]) : less4(v[i], v[l]);
          if (sw){ uint4 tmp = v[i]; v[i] = v[l]; v[l] = tmp; }
        }
      }
    }
  }
  #pragma unroll
  for (int e = 0; e < 4; ++e) sh[SWV(k0 + e)] = v[e];
  __syncthreads();
  // LDS merge-path rounds: run width w -> 2w
  for (int w = 4; w < VT; w <<= 1){
    int base = k0 & ~(2*w - 1);
    int ko = k0 - base;
    int lo = ko - w; if (lo < 0) lo = 0;
    int hi = ko < w ? ko : w;
    while (lo < hi){
      int mid = (lo + hi) >> 1;
      if (less4(sh[SWV(base + mid)], sh[SWV(base + w + ko-1-mid)])) lo = mid + 1; else hi = mid;
    }
    int i = lo, j = ko - lo;
    uint4 m[4];
    #pragma unroll
    for (int e = 0; e < 4; ++e){
      bool takeA = (j >= w) || (i < w && less4(sh[SWV(base + i)], sh[SWV(base + w + j)]));
      m[e] = takeA ? sh[SWV(base + i)] : sh[SWV(base + w + j)];
      if (takeA) ++i; else ++j;
    }
    __syncthreads();
    #pragma unroll
    for (int e = 0; e < 4; ++e) sh[SWV(k0 + e)] = m[e];
    __syncthreads();
  }
  uint4* basep = S + (size_t)blockBase;
  for (int i = threadIdx.x; i < VT; i += 1024) basep[i] = sh[SWV(i)];
}

// ---------------- LDS-staged merge-path merge rounds --------------------------
// Chunk 1024 recs/block: more blocks/CU (16 KB LDS) -> more parallel searches.
__global__ __launch_bounds__(256) void kmergev(const uint4* __restrict__ src,
                                               uint4* __restrict__ dst, int L){
  __shared__ uint4 sh[1024];
  __shared__ int sAB[2];
  int gid = blockIdx.x;
  int b = gid >> 5, c = gid & 31;           // 32 chunks of 1024 per batch
  const uint4* base = src + ((size_t)b << 15);
  uint4* obase = dst + ((size_t)b << 15);
  int co = c * 1024;
  int pair = co / (2*L);
  int ko = co - pair*2*L;
  const uint4* A = base + (size_t)pair*2*L;
  const uint4* B = A + L;
  uint4* O = obase + (size_t)pair*2*L + ko;
  if (threadIdx.x < 2){
    int k = ko + (int)threadIdx.x * 1024;
    int lo = k - L; if (lo < 0) lo = 0;
    int hi = k < L ? k : L;
    while (lo < hi){
      int mid = (lo + hi) >> 1;
      if (less4(A[mid], B[k-1-mid])) lo = mid + 1; else hi = mid;
    }
    sAB[threadIdx.x] = lo;
  }
  __syncthreads();
  int aStart = sAB[0];
  int na = sAB[1] - aStart;
  int nb = 1024 - na;
  int bStart = ko - aStart;
  for (int i = threadIdx.x; i < 1024; i += 256)
    sh[i] = (i < na) ? A[aStart + i] : B[bStart + (i - na)];
  __syncthreads();
  int k0 = threadIdx.x * 4;
  int lo = k0 - nb; if (lo < 0) lo = 0;
  int hi = k0 < na ? k0 : na;
  while (lo < hi){
    int mid = (lo + hi) >> 1;
    if (less4(sh[mid], sh[na + k0-1-mid])) lo = mid + 1; else hi = mid;
  }
  int i = lo, j = k0 - lo;
  #pragma unroll
  for (int e = 0; e < 4; ++e){
    bool takeA = (j >= nb) || (i < na && less4(sh[i], sh[na + j]));
    uint4 v = takeA ? sh[i] : sh[na + j];
    if (takeA) ++i; else ++j;
    O[k0 + e] = v;
  }
}

// Final vertex merge (L=16384) fused with inverse-permutation + packed quant
// table: the merged record never round-trips through global sorted S.
__global__ __launch_bounds__(256) void kmergevQ(const uint4* __restrict__ src,
                                                int* __restrict__ inv,
                                                unsigned* __restrict__ Q){
  #pragma clang fp contract(off)
  __shared__ uint4 sh[1024];
  __shared__ int sAB[2];
  const int L = 16384;
  int gid = blockIdx.x;
  int b = gid >> 5, c = gid & 31;
  const uint4* A = src + ((size_t)b << 15);
  const uint4* B = A + L;
  int ko = c * 1024;                          // pair==0 (2L == NV)
  if (threadIdx.x < 2){
    int k = ko + (int)threadIdx.x * 1024;
    int lo = k - L; if (lo < 0) lo = 0;
    int hi = k < L ? k : L;
    while (lo < hi){
      int mid = (lo + hi) >> 1;
      if (less4(A[mid], B[k-1-mid])) lo = mid + 1; else hi = mid;
    }
    sAB[threadIdx.x] = lo;
  }
  __syncthreads();
  int aStart = sAB[0];
  int na = sAB[1] - aStart;
  int nb = 1024 - na;
  int bStart = ko - aStart;
  for (int i = threadIdx.x; i < 1024; i += 256)
    sh[i] = (i < na) ? A[aStart + i] : B[bStart + (i - na)];
  __syncthreads();
  int k0 = threadIdx.x * 4;
  int lo = k0 - nb; if (lo < 0) lo = 0;
  int hi = k0 < na ? k0 : na;
  while (lo < hi){
    int mid = (lo + hi) >> 1;
    if (less4(sh[mid], sh[na + k0-1-mid])) lo = mid + 1; else hi = mid;
  }
  int i = lo, j = k0 - lo;
  #pragma unroll
  for (int e = 0; e < 4; ++e){
    bool takeA = (j >= nb) || (i < na && less4(sh[i], sh[na + j]));
    uint4 s = takeA ? sh[i] : sh[na + j];
    if (takeA) ++i; else ++j;
    int pos = ko + k0 + e;                    // final sorted index within batch
    inv[(b<<15) + (int)s.w] = pos;
    float cco[3]; cco[0] = fdec(s.z); cco[1] = fdec(s.y); cco[2] = fdec(s.x); // (x,y,z)
    unsigned qw = 0;
    #pragma unroll
    for (int cc = 0; cc < 3; ++cc){
      float tt = ((cco[cc] + 1.0f) * 0.5f) * 128.0f - 0.5f;
      float rq = rintf(tt);
      int qi = (int)rq;
      qi = qi < 0 ? 0 : (qi > 127 ? 127 : qi);
      qw |= ((unsigned)qi) << (8*cc);
    }
    Q[(b<<15) + pos] = qw;
  }
}

// Fused face keygen + OUTPUT EMISSION + blocksort, with XCD-affine swizzle.
// Swizzle l=(p%8)*32+p/8 (bijective, 256=8x32): XCD x serves batches 4x..4x+3
// only -> inv+Q working set 1MB, L2-resident. 1024 threads: 16 waves/CU.
__global__ __launch_bounds__(1024) void klocalfB(const int* __restrict__ faces,
                                                 const int* __restrict__ inv,
                                                 const unsigned* __restrict__ Qt,
                                                 uint2* __restrict__ F,
                                                 float* __restrict__ out){
  __shared__ __align__(16) uint2 sh[FT];      // 64 KB; first 40KB doubles as scratch
  float* shq = (float*)sh;                    // [9216] staging (36 KB)
  float* shm = ((float*)sh) + 9216;           // [1024] masks (4 KB)
  int p = blockIdx.x;
  int l = ((p & 7) << 5) | (p >> 3);          // XCD-affine, bijective on 256
  int blockBase = l * FT;                     // tiles never cross batch boundary
  int b = blockBase >> 16;
  const int* invb = inv + (b << 15);
  const unsigned* Qb = Qt + (b << 15);
  int t = threadIdx.x;
  uint2 v[8];
  #pragma unroll 8
  for (int c = 0; c < 8; ++c){
    int i = c*1024 + t;
    int id = blockBase + i;
    int f = id & (NF-1);
    size_t fb = (size_t)id*3;
    int f0 = faces[fb+0], f1 = faces[fb+1], f2 = faces[fb+2];
    bool mask = (f0 != -1) & (f1 != -1) & (f2 != -1);
    unsigned r0 = (unsigned)invb[f0 & (NV-1)];
    unsigned r1 = (unsigned)invb[f1 & (NV-1)];
    unsigned r2 = (unsigned)invb[f2 & (NV-1)];
    v[c].x = (r0 << 15) | (unsigned)f;
    v[c].y = (r2 << 15) | r1;
    unsigned qw0 = Qb[mask ? f0 : 0];
    unsigned qw1 = Qb[mask ? f1 : 0];
    unsigned qw2 = Qb[mask ? f2 : 0];
    shm[t] = mask ? 1.0f : 0.0f;
    shq[t*9+0] = (float)( qw0        & 255u);
    shq[t*9+1] = (float)((qw0 >> 8 ) & 255u);
    shq[t*9+2] = (float)((qw0 >> 16) & 255u);
    shq[t*9+3] = (float)( qw1        & 255u);
    shq[t*9+4] = (float)((qw1 >> 8 ) & 255u);
    shq[t*9+5] = (float)((qw1 >> 16) & 255u);
    shq[t*9+6] = (float)( qw2        & 255u);
    shq[t*9+7] = (float)((qw2 >> 8 ) & 255u);
    shq[t*9+8] = (float)((qw2 >> 16) & 255u);
    __syncthreads();
    // codes/dq: 16B-aligned chunk bases -> float4 stores (2304 per chunk)
    float4* cp = (float4*)(out + 37748864 + ((size_t)blockBase + c*1024)*9);
    float4* dp = (float4*)(out + 56623232 + ((size_t)blockBase + c*1024)*9);
    for (int r = t; r < 2304; r += 1024){
      int e0 = r*4;
      float4 q = *(const float4*)&shq[e0];
      float m0 = shm[(unsigned)(e0  )/9u];
      float m1 = shm[(unsigned)(e0+1)/9u];
      float m2 = shm[(unsigned)(e0+2)/9u];
      float m3 = shm[(unsigned)(e0+3)/9u];
      float4 cv;
      cv.x = m0 != 0.0f ? q.x : -1.0f;
      cv.y = m1 != 0.0f ? q.y : -1.0f;
      cv.z = m2 != 0.0f ? q.z : -1.0f;
      cv.w = m3 != 0.0f ? q.w : -1.0f;
      cp[r] = cv;
      dp[r] = q;
    }
    // ids/attn: +1 float offset (misaligned) -> dense scalar dword stores
    size_t fi = (size_t)(blockBase & (NF-1)) + (size_t)c*1024;  // within batch
    size_t idsBase  = (size_t)b*589826 + 1 + fi*9;
    size_t attnBase = 18874432 + idsBase;
    #pragma unroll
    for (int r = 0; r < 9; ++r){
      int idx = r*1024 + t;
      float q = shq[idx];
      float m = shm[(unsigned)idx/9u];
      out[idsBase + idx]  = m != 0.0f ? q : -1.0f;
      out[attnBase + idx] = m;
    }
    __syncthreads();                          // shq/shm reuse (and final: FK reuse)
  }
  if ((blockBase & (NF-1)) == 0 && t == 0){
    out[(size_t)b*589826]                     = -1.0f;
    out[(size_t)b*589826 + 589825]            = -1.0f;
    out[18874432 + (size_t)b*589826]          = -1.0f;
    out[18874432 + (size_t)b*589826 + 589825] = -1.0f;
  }
  // in-register bitonic sort of 8 (any 8 elements -> sorted run; total order
  // makes the final sorted tile independent of initial placement)
  #pragma unroll
  for (int k = 2; k <= 8; k <<= 1){
    #pragma unroll
    for (int j = k >> 1; j > 0; j >>= 1){
      #pragma unroll
      for (int i = 0; i < 8; ++i){
        int l2 = i ^ j;
        if (l2 > i){
          bool up = ((i & k) == 0);
          bool sw = up ? less2(v[l2], v[i]) : less2(v[i], v[l2]);
          if (sw){ uint2 tmp = v[i]; v[i] = v[l2]; v[l2] = tmp; }
        }
      }
    }
  }
  int k0 = t * 8;
  #pragma unroll
  for (int e = 0; e < 8; ++e) sh[SWF(k0 + e)] = v[e];
  __syncthreads();
  for (int w = 8; w < FT; w <<= 1){
    int base = k0 & ~(2*w - 1);
    int ko = k0 - base;
    int lo = ko - w; if (lo < 0) lo = 0;
    int hi = ko < w ? ko : w;
    while (lo < hi){
      int mid = (lo + hi) >> 1;
      if (less2(sh[SWF(base + mid)], sh[SWF(base + w + ko-1-mid)])) lo = mid + 1; else hi = mid;
    }
    int i = lo, j = ko - lo;
    uint2 m[8];
    #pragma unroll
    for (int e = 0; e < 8; ++e){
      bool takeA = (j >= w) || (i < w && less2(sh[SWF(base + i)], sh[SWF(base + w + j)]));
      m[e] = takeA ? sh[SWF(base + i)] : sh[SWF(base + w + j)];
      if (takeA) ++i; else ++j;
    }
    __syncthreads();
    #pragma unroll
    for (int e = 0; e < 8; ++e) sh[SWF(k0 + e)] = m[e];
    __syncthreads();
  }
  uint2* basep = F + (size_t)blockBase;
  for (int i = threadIdx.x; i < FT; i += 1024) basep[i] = sh[SWF(i)];
}

// Chunk 1024: grid BATCH*64, 8 KB LDS -> high blocks/CU.
__global__ __launch_bounds__(256) void kmergef(const uint2* __restrict__ src,
                                               uint2* __restrict__ dst, int L){
  __shared__ uint2 sh[1024];
  __shared__ int sAB[2];
  int gid = blockIdx.x;
  int b = gid >> 6, c = gid & 63;           // 64 chunks of 1024 per batch
  const uint2* base = src + ((size_t)b << 16);
  uint2* obase = dst + ((size_t)b << 16);
  int co = c * 1024;
  int pair = co / (2*L);
  int ko = co - pair*2*L;
  const uint2* A = base + (size_t)pair*2*L;
  const uint2* B = A + L;
  uint2* O = obase + (size_t)pair*2*L + ko;
  if (threadIdx.x < 2){
    int k = ko + (int)threadIdx.x * 1024;
    int lo = k - L; if (lo < 0) lo = 0;
    int hi = k < L ? k : L;
    while (lo < hi){
      int mid = (lo + hi) >> 1;
      if (less2(A[mid], B[k-1-mid])) lo = mid + 1; else hi = mid;
    }
    sAB[threadIdx.x] = lo;
  }
  __syncthreads();
  int aStart = sAB[0];
  int na = sAB[1] - aStart;
  int nb = 1024 - na;
  int bStart = ko - aStart;
  for (int i = threadIdx.x; i < 1024; i += 256)
    sh[i] = (i < na) ? A[aStart + i] : B[bStart + (i - na)];
  __syncthreads();
  int k0 = threadIdx.x * 4;
  int lo = k0 - nb; if (lo < 0) lo = 0;
  int hi = k0 < na ? k0 : na;
  while (lo < hi){
    int mid = (lo + hi) >> 1;
    if (less2(sh[mid], sh[na + k0-1-mid])) lo = mid + 1; else hi = mid;
  }
  int i = lo, j = k0 - lo;
  #pragma unroll
  for (int e = 0; e < 4; ++e){
    bool takeA = (j >= nb) || (i < na && less2(sh[i], sh[na + j]));
    uint2 v = takeA ? sh[i] : sh[na + j];
    if (takeA) ++i; else ++j;
    O[k0 + e] = v;
  }
}

// Final face merge (L=32768): merge in LDS, decode ranks, write sorted_faces
// floats directly (3 dense streams).
__global__ __launch_bounds__(256) void kmergefOut(const uint2* __restrict__ src,
                                                  float* __restrict__ out){
  __shared__ __align__(16) float shf[3072];   // 12 KB; aliased as uint2[1024] below
  __shared__ int sAB[2];
  uint2* sh = (uint2*)shf;
  const int L = 32768;
  int gid = blockIdx.x;                       // 2048 = 32 batches x 64 chunks
  int b = gid >> 6, c = gid & 63;
  const uint2* A = src + ((size_t)b << 16);
  const uint2* B = A + L;
  int ko = c * 1024;
  if (threadIdx.x < 2){
    int k = ko + (int)threadIdx.x * 1024;
    int lo = k - L; if (lo < 0) lo = 0;
    int hi = k < L ? k : L;
    while (lo < hi){
      int mid = (lo + hi) >> 1;
      if (less2(A[mid], B[k-1-mid])) lo = mid + 1; else hi = mid;
    }
    sAB[threadIdx.x] = lo;
  }
  __syncthreads();
  int aStart = sAB[0];
  int na = sAB[1] - aStart;
  int nb = 1024 - na;
  int bStart = ko - aStart;
  for (int i = threadIdx.x; i < 1024; i += 256)
    sh[i] = (i < na) ? A[aStart + i] : B[bStart + (i - na)];
  __syncthreads();
  int k0 = threadIdx.x * 4;
  int lo = k0 - nb; if (lo < 0) lo = 0;
  int hi = k0 < na ? k0 : na;
  while (lo < hi){
    int mid = (lo + hi) >> 1;
    if (less2(sh[mid], sh[na + k0-1-mid])) lo = mid + 1; else hi = mid;
  }
  int i = lo, j = k0 - lo;
  uint2 v[4];
  #pragma unroll
  for (int e = 0; e < 4; ++e){
    bool takeA = (j >= nb) || (i < na && less2(sh[i], sh[na + j]));
    v[e] = takeA ? sh[i] : sh[na + j];
    if (takeA) ++i; else ++j;
  }
  __syncthreads();                            // all LDS src reads done
  #pragma unroll
  for (int e = 0; e < 4; ++e){
    int o = (k0 + e) * 3;
    shf[o+0] = (float)(v[e].x >> 15);         // r0
    shf[o+1] = (float)(v[e].y & 0x7FFFu);     // r1
    shf[o+2] = (float)(v[e].y >> 15);         // r2
  }
  __syncthreads();
  size_t basef = 75497600 + ((size_t)b*65536 + (size_t)ko)*3;
  for (int q = threadIdx.x; q < 3072; q += 256) out[basef + q] = shf[q];
}
// -----------------------------------------------------------------------------

extern "C" void kernel_launch(void* const* d_in, const int* in_sizes, int n_in,
                              void* d_out, int out_size, void* d_ws, size_t ws_size,
                              hipStream_t stream){
  const float* vert  = (const float*)d_in[0];
  const int*   faces = (const int*)d_in[1];
  float* out = (float*)d_out;

  uint4*    S           = (uint4*)d_ws;                         // 16 MiB
  uint4*    S2          = (uint4*)((char*)d_ws + 16777216);     // 16 MiB
  uint2*    FKa         = (uint2*)((char*)d_ws + 16777216);     // reuses S2
  unsigned* Q           = (unsigned*)((char*)d_ws + 16777216);  // aliases FKa (4 MiB)
  uint2*    FKb         = (uint2*)d_ws;                         // reuses S
  int*      inv         = (int*)((char*)d_ws + 33554432);       // 4 MiB
  float*    center      = (float*)((char*)d_ws + 37748736);     // 384 KiB
  unsigned* longestBits = (unsigned*)((char*)d_ws + 38141952);  // 4 B

  hipMemsetAsync(longestBits, 0, 4, stream);
  kminmax<<<PCOUNT/256, 256, 0, stream>>>(vert, center, longestBits);

  // vertex sort: fused keygen + blocksort 4096-tiles, 2 merge rounds,
  // final round fused with inv+Q emission (sorted S never re-materialized)
  klocalv<<<BATCH*(NV/VT), 1024, 0, stream>>>(vert, center, longestBits, S);
  kmergev<<<BATCH*32, 256, 0, stream>>>(S,  S2, 4096);
  kmergev<<<BATCH*32, 256, 0, stream>>>(S2, S,  8192);
  kmergevQ<<<BATCH*32, 256, 0, stream>>>(S, inv, Q);            // S dead after

  // fused face keygen + output emission + blocksort (XCD-swizzled gathers)
  klocalfB<<<BATCH*(NF/FT), 1024, 0, stream>>>(faces, inv, Q, FKb, out);  // Q dead

  kmergef<<<BATCH*64, 256, 0, stream>>>(FKb, FKa, 8192);
  kmergef<<<BATCH*64, 256, 0, stream>>>(FKa, FKb, 16384);
  kmergefOut<<<BATCH*64, 256, 0, stream>>>(FKb, out);
}